// Round 14
// baseline (189.550 us; speedup 1.0000x reference)
//
#include <hip/hip_runtime.h>
#include <stdint.h>

typedef int   v4i  __attribute__((ext_vector_type(4)));
typedef int   v8i  __attribute__((ext_vector_type(8)));
typedef float v16f __attribute__((ext_vector_type(16)));
typedef unsigned int uint32;

#define BATCH 16384
#define FEAT  1024

// ---- workspace layout (bytes) ----
// MXFP4 everywhere (+1=0x2, -1=0xA, pad=0x0). Frag = 64 lanes x 16B = K=64.
// Logical k (hi=lane>>5, i) of frag f -> model index rho = 64f + (i>>4)*32 +
// sigma4(i&15) + 4*hi, sigma4(q) = (q&3)+8*(q>>2). Producer C-register nibbles
// land verbatim in the consumer B-frag slot (R12-verified). W sign-folded;
// thresholds in sigma order init the f32 accumulator (exact integers).
#define OFF_ACTA 0u            // 8 MB  (packed X, fp4)
#define OFF_ACTB 16777216u     // (unused — kept for layout stability)
#define OFF_WA1  33554432u     // 512 KB
#define OFF_WA2  34603008u     // 512 KB
#define OFF_WA3  35651584u     // 512 KB
#define OFF_WA4  36700160u     // 16 KB (10 rows + 22 zero rows)
#define OFF_TH   36732928u     // 3*1024 int (sigma order)

// ---------------------------------------------------------------------------
// bytes {0x01,0xFF,0x00} -> fp4 nibbles {+1=0x2,-1=0xA,0=0x0}; 8 bytes -> dword
__device__ __forceinline__ uint32 nib8(uint32 lo, uint32 hb) {
    uint32 r = 0u;
#pragma unroll
    for (int j = 0; j < 4; ++j) {
        uint32 b = (lo >> (8 * j)) & 0xFFu;
        r |= (((b & 8u) | ((b & 1u) << 1)) << (4 * j));
    }
#pragma unroll
    for (int j = 0; j < 4; ++j) {
        uint32 b = (hb >> (8 * j)) & 0xFFu;
        r |= (((b & 8u) | ((b & 1u) << 1)) << (4 * j + 16));
    }
    return r;
}

// ---------------------------------------------------------------------------
// prep (R12-verified, unchanged): binarize, sign-fold W, emit fp4 rho frags.
__global__ void __launch_bounds__(256) prep_kernel(
    const float* __restrict__ x,
    const float* __restrict__ W1, const float* __restrict__ W2,
    const float* __restrict__ W3, const float* __restrict__ W4,
    const float* __restrict__ g1, const float* __restrict__ b1,
    const float* __restrict__ m1, const float* __restrict__ v1,
    const float* __restrict__ g2, const float* __restrict__ b2,
    const float* __restrict__ m2, const float* __restrict__ v2,
    const float* __restrict__ g3, const float* __restrict__ b3,
    const float* __restrict__ m3, const float* __restrict__ v3,
    char* __restrict__ actA, char* __restrict__ wa1, char* __restrict__ wa2,
    char* __restrict__ wa3, char* __restrict__ wa4, int* __restrict__ TH)
{
    int b = blockIdx.x;
    if (b == 609) {                       // thresholds, sign-folded, sigma order
        for (int gid = threadIdx.x; gid < 3072; gid += 256) {
            int l = gid >> 10, j = gid & 1023;
            const float *g, *bb, *m, *v;
            if (l == 0)      { g = g1; bb = b1; m = m1; v = v1; }
            else if (l == 1) { g = g2; bb = b2; m = m2; v = v2; }
            else             { g = g3; bb = b3; m = m3; v = v3; }
            double gd = (double)g[j], bd = (double)bb[j], md = (double)m[j], vd = (double)v[j];
            double s = gd / sqrt(vd + 1e-5);
            int t2;
            if (s > 0.0)      t2 = (int)ceil(md - bd / s);           // bit = h >= t2
            else if (s < 0.0) t2 = -(int)floor(md - bd / s);         // folded
            else              t2 = (bd >= 0.0) ? -2000000 : 2000000; // always / never
            int sidx = (j >> 5) * 32 + ((j >> 2) & 1) * 16 + (j & 3) + 4 * ((j & 31) >> 3);
            TH[l * 1024 + sidx] = t2;
        }
        return;
    }

    const float* src; char* dst; float thr; int nrows; int dblk;
    const float* gp = nullptr;
    if (b < 512)      { src = x  + (size_t)b * 32768;            dst = actA; dblk = b;      thr = 0.5f; nrows = 32; }
    else if (b < 544) { int mb = b - 512; src = W1 + (size_t)mb * 32768; dst = wa1; dblk = mb; thr = 0.0f; nrows = 32; gp = g1; }
    else if (b < 576) { int mb = b - 544; src = W2 + (size_t)mb * 32768; dst = wa2; dblk = mb; thr = 0.0f; nrows = 32; gp = g2; }
    else if (b < 608) { int mb = b - 576; src = W3 + (size_t)mb * 32768; dst = wa3; dblk = mb; thr = 0.0f; nrows = 32; gp = g3; }
    else              { src = W4; dst = wa4; dblk = 0; thr = 0.0f; nrows = 10; }

    __shared__ unsigned char T[32][1040];
#pragma unroll
    for (int u = 0; u < 8; ++u) {
        int unit = threadIdx.x + u * 256;      // 0..2047
        int row  = unit >> 6;                  // 0..31
        int c16  = (unit & 63) << 4;           // col base (16 floats)
        uint32 wb0 = 0, wb1 = 0, wb2 = 0, wb3 = 0;   // 0x00 pad rows -> fp4 zero
        if (row < nrows) {
            bool flipb = gp && (gp[dblk * 32 + row] < 0.0f);
            const float* p = src + (size_t)row * 1024 + c16;
            float4 f0 = *(const float4*)(p + 0);
            float4 f1 = *(const float4*)(p + 4);
            float4 f2 = *(const float4*)(p + 8);
            float4 f3 = *(const float4*)(p + 12);
#define BY(f) ((((f) >= thr) != flipb) ? 0x01u : 0xFFu)
            wb0 = BY(f0.x) | (BY(f0.y)<<8) | (BY(f0.z)<<16) | (BY(f0.w)<<24);
            wb1 = BY(f1.x) | (BY(f1.y)<<8) | (BY(f1.z)<<16) | (BY(f1.w)<<24);
            wb2 = BY(f2.x) | (BY(f2.y)<<8) | (BY(f2.z)<<16) | (BY(f2.w)<<24);
            wb3 = BY(f3.x) | (BY(f3.y)<<8) | (BY(f3.z)<<16) | (BY(f3.w)<<24);
#undef BY
        }
        *(uint4*)&T[row][c16] = make_uint4(wb0, wb1, wb2, wb3);
    }
    __syncthreads();

    int lane = threadIdx.x & 63;
    int wq   = threadIdx.x >> 6;               // 0..3
    int c    = lane & 31;
    int hi   = lane >> 5;
#pragma unroll
    for (int u = 0; u < 4; ++u) {
        int f = wq * 4 + u;
        uint32 dw0, dw1, dw2, dw3;
        {
            int base = 64 * f + 4 * hi;
            dw0 = nib8(*(const uint32*)&T[c][base],      *(const uint32*)&T[c][base + 8]);
            dw1 = nib8(*(const uint32*)&T[c][base + 16], *(const uint32*)&T[c][base + 24]);
            dw2 = nib8(*(const uint32*)&T[c][base + 32], *(const uint32*)&T[c][base + 40]);
            dw3 = nib8(*(const uint32*)&T[c][base + 48], *(const uint32*)&T[c][base + 56]);
        }
        *(uint4*)(dst + (((size_t)dblk * 16 + f) * 64 + lane) * 16) = make_uint4(dw0, dw1, dw2, dw3);
    }
}

// ---------------------------------------------------------------------------
__device__ __forceinline__ void gload16(const v4i* gsrc, v4i* ldst) {
    __builtin_amdgcn_global_load_lds(
        (const __attribute__((address_space(1))) void*)gsrc,
        (__attribute__((address_space(3))) void*)ldst, 16, 0, 0);
}

// fp4 MX MFMA, scale = 1.0 (E8M0 0x7F); cbsz=4 (fp4), blgp=4 (fp4)
__device__ __forceinline__ v16f MFMA4(v4i a, v4i b, v16f c) {
    v8i av; av[0] = a[0]; av[1] = a[1]; av[2] = a[2]; av[3] = a[3];
    av[4] = 0; av[5] = 0; av[6] = 0; av[7] = 0;
    v8i bv; bv[0] = b[0]; bv[1] = b[1]; bv[2] = b[2]; bv[3] = b[3];
    bv[4] = 0; bv[5] = 0; bv[6] = 0; bv[7] = 0;
    return __builtin_amdgcn_mfma_scale_f32_32x32x64_f8f6f4(
        av, bv, c, 4, 4, 0, 0x7F7F7F7F, 0, 0x7F7F7F7F);
}

// ---------------------------------------------------------------------------
// R14 = R13 resubmitted (container infra failure, kernel never ran).
// Net: R12 fp4 kernel + W streamed through a 2x32KB LDS double-buffer via
// global_load_lds (zero-VGPR staging -- the only prefetch mechanism that
// survives the 128-VGPR cap; R9/R11 register routes spilled). Per f-step:
// issue stage of frag f+1 (all 32 m-tiles, 2 gload16/thread) -> ds_read A
// from Wb[cur] + B from Hs -> 4 MFMAs -> vmcnt(0) (stages issued ~700cyc ago,
// free) + barrier. fs=15 stages the NEXT layer's f0, so layers chain.
// LDS 96 KB -> 1 block/CU; per-CU W traffic halves.
__global__ void __launch_bounds__(1024, 4) net_kernel(
    const v4i* __restrict__ Xp,  const v4i* __restrict__ Wp1,
    const v4i* __restrict__ Wp2, const v4i* __restrict__ Wp3,
    const v4i* __restrict__ Wp4, const int* __restrict__ TH,
    const float* __restrict__ tw, const float* __restrict__ tb,
    const float* __restrict__ tm, const float* __restrict__ tv,
    float* __restrict__ out)
{
    __shared__ v4i Hs[2048];               // 32 KB: frag g = nb*16+f at g*64+lane
    __shared__ v4i Wb[2][2048];            // 2 x 32 KB: Wb[buf][mt*64+lane]
    const int tid  = threadIdx.x;
    const int lane = tid & 63;
    const int wv   = tid >> 6;             // 0..15
    const int hi   = lane >> 5;
    const int blk  = blockIdx.x;           // 0..255, owns cols blk*64..+63

    // ---- X into Hs + stage layer-0 frag 0 into Wb[0] (all async) ----
    {
        const v4i* src = Xp + (size_t)blk * 2048;
#pragma unroll
        for (int j = 0; j < 2; ++j)
            gload16(src + j * 1024 + wv * 64 + lane, &Hs[j * 1024 + wv * 64]);
        gload16(Wp1 + (size_t)(wv * 16) * 64 + lane,        &Wb[0][wv * 64]);
        gload16(Wp1 + (size_t)((16 + wv) * 16) * 64 + lane, &Wb[0][1024 + wv * 64]);
    }
    asm volatile("s_waitcnt vmcnt(0)" ::: "memory");
    __syncthreads();

    const int mt0 = wv * 2, mt1 = wv * 2 + 1;

#pragma unroll 1
    for (int l = 0; l < 3; ++l) {
        const v4i* W = (l == 0) ? Wp1 : (l == 1) ? Wp2 : Wp3;
        const int* thl = TH + l * 1024;

        // f32 acc pre-initialized with -T2 (exact integers)
        v16f acc00, acc01, acc10, acc11;
        {
            const int4* t0 = (const int4*)(thl + mt0 * 32 + hi * 16);
            const int4* t1 = (const int4*)(thl + mt1 * 32 + hi * 16);
#pragma unroll
            for (int g = 0; g < 4; ++g) {
                int4 ta = t0[g], tc = t1[g];
                acc00[4*g+0] = -(float)ta.x; acc00[4*g+1] = -(float)ta.y;
                acc00[4*g+2] = -(float)ta.z; acc00[4*g+3] = -(float)ta.w;
                acc10[4*g+0] = -(float)tc.x; acc10[4*g+1] = -(float)tc.y;
                acc10[4*g+2] = -(float)tc.z; acc10[4*g+3] = -(float)tc.w;
            }
#pragma unroll
            for (int q = 0; q < 16; ++q) { acc01[q] = acc00[q]; acc11[q] = acc10[q]; }
        }

#pragma unroll 1
        for (int fs = 0; fs < 16; ++fs) {
            const int cur = fs & 1;
            const v4i* Wc = &Wb[cur][0];
            v4i* Wn = &Wb[cur ^ 1][0];
            if (fs < 15) {                      // stage next frag of this layer
                gload16(W + (size_t)(wv * 16 + fs + 1) * 64 + lane,        Wn + wv * 64);
                gload16(W + (size_t)((16 + wv) * 16 + fs + 1) * 64 + lane, Wn + 1024 + wv * 64);
            } else if (l < 2) {                 // stage next layer's frag 0
                const v4i* W2 = (l == 0) ? Wp2 : Wp3;
                gload16(W2 + (size_t)(wv * 16) * 64 + lane,        Wn + wv * 64);
                gload16(W2 + (size_t)((16 + wv) * 16) * 64 + lane, Wn + 1024 + wv * 64);
            }
            v4i a0 = Wc[mt0 * 64 + lane];
            v4i a1 = Wc[mt1 * 64 + lane];
            v4i b0 = Hs[fs * 64 + lane];
            v4i b1 = Hs[(16 + fs) * 64 + lane];
            acc00 = MFMA4(a0, b0, acc00);
            acc01 = MFMA4(a0, b1, acc01);
            acc10 = MFMA4(a1, b0, acc10);
            acc11 = MFMA4(a1, b1, acc11);
            // stages (2/thread, issued above) must land before next step reads;
            // they were issued ~a full LDS-bound step ago -> drain is ~free.
            asm volatile("s_waitcnt vmcnt(0)" ::: "memory");
            __builtin_amdgcn_s_barrier();
        }

        // pack: nibble = 0x2 (+1) if h>=0 else 0xA (-1)
#define NB4(h) (((h) >= 0.0f) ? 2u : 10u)
        uint32 p00a = 0, p00b = 0, p01a = 0, p01b = 0;
        uint32 p10a = 0, p10b = 0, p11a = 0, p11b = 0;
#pragma unroll
        for (int j = 0; j < 8; ++j) {
            p00a |= NB4(acc00[j]) << (4 * j);  p00b |= NB4(acc00[8 + j]) << (4 * j);
            p01a |= NB4(acc01[j]) << (4 * j);  p01b |= NB4(acc01[8 + j]) << (4 * j);
            p10a |= NB4(acc10[j]) << (4 * j);  p10b |= NB4(acc10[8 + j]) << (4 * j);
            p11a |= NB4(acc11[j]) << (4 * j);  p11b |= NB4(acc11[8 + j]) << (4 * j);
        }
#undef NB4

        __syncthreads();                   // all waves done READING Hs
        {
            v4i o;
            o[0] = (int)p00a; o[1] = (int)p00b; o[2] = (int)p10a; o[3] = (int)p10b;
            Hs[(0 * 16 + wv) * 64 + lane] = o;       // nb0
            o[0] = (int)p01a; o[1] = (int)p01b; o[2] = (int)p11a; o[3] = (int)p11b;
            Hs[(16 + wv) * 64 + lane] = o;           // nb1
        }
        __syncthreads();                   // new layer visible to all waves
    }

    // ---- final 1024 -> 10 (W4 zero-padded rows = fp4 0.0) + TensorNorm ----
    if (wv < 2) {
        const int nb = wv;
        v16f acc;
#pragma unroll
        for (int z = 0; z < 16; ++z) acc[z] = 0.0f;
#pragma unroll
        for (int f = 0; f < 16; ++f) {
            v4i av = Wp4[f * 64 + lane];
            v4i bv = Hs[(nb * 16 + f) * 64 + lane];
            acc = MFMA4(av, bv, acc);
        }
        double sc  = (double)tw[0] / sqrt((double)tv[0] + 1e-4);
        double off = (double)tb[0] - (double)tm[0] * sc;
        int colg = blk * 64 + nb * 32 + (lane & 31);
#pragma unroll
        for (int q = 0; q < 8; ++q) {
            int rr = (q & 3) + 8 * (q >> 2) + 4 * hi;
            if (rr < 10)
                out[(size_t)colg * 10 + rr] = (float)((double)acc[q] * sc + off);
        }
    }
}

// ---------------------------------------------------------------------------
extern "C" void kernel_launch(void* const* d_in, const int* in_sizes, int n_in,
                              void* d_out, int out_size, void* d_ws, size_t ws_size,
                              hipStream_t stream) {
    const float* x  = (const float*)d_in[0];
    const float* W1 = (const float*)d_in[1];
    const float* W2 = (const float*)d_in[2];
    const float* W3 = (const float*)d_in[3];
    const float* W4 = (const float*)d_in[4];
    const float* g1 = (const float*)d_in[5];
    const float* b1 = (const float*)d_in[6];
    const float* m1 = (const float*)d_in[7];
    const float* v1 = (const float*)d_in[8];
    const float* g2 = (const float*)d_in[9];
    const float* b2 = (const float*)d_in[10];
    const float* m2 = (const float*)d_in[11];
    const float* v2 = (const float*)d_in[12];
    const float* g3 = (const float*)d_in[13];
    const float* b3 = (const float*)d_in[14];
    const float* m3 = (const float*)d_in[15];
    const float* v3 = (const float*)d_in[16];
    const float* tw = (const float*)d_in[17];
    const float* tb = (const float*)d_in[18];
    const float* tm = (const float*)d_in[19];
    const float* tv = (const float*)d_in[20];

    char* ws = (char*)d_ws;
    char* actA = ws + OFF_ACTA;
    char* wa1  = ws + OFF_WA1;
    char* wa2  = ws + OFF_WA2;
    char* wa3  = ws + OFF_WA3;
    char* wa4  = ws + OFF_WA4;
    int*  TH   = (int*)(ws + OFF_TH);

    prep_kernel<<<610, 256, 0, stream>>>(x, W1, W2, W3, W4,
                                         g1, b1, m1, v1, g2, b2, m2, v2,
                                         g3, b3, m3, v3,
                                         actA, wa1, wa2, wa3, wa4, TH);

    net_kernel<<<256, 1024, 0, stream>>>((const v4i*)actA,
                                         (const v4i*)wa1, (const v4i*)wa2,
                                         (const v4i*)wa3, (const v4i*)wa4,
                                         TH, tw, tb, tm, tv, (float*)d_out);
}

// Round 15
// 183.440 us; speedup vs baseline: 1.0333x; 1.0333x over previous
//
#include <hip/hip_runtime.h>
#include <stdint.h>

typedef int   v4i  __attribute__((ext_vector_type(4)));
typedef int   v8i  __attribute__((ext_vector_type(8)));
typedef float v16f __attribute__((ext_vector_type(16)));
typedef unsigned int uint32;

#define BATCH 16384
#define FEAT  1024

// ---- workspace layout (bytes) ----
// MXFP4 everywhere (+1=0x2, -1=0xA, pad=0x0). Frag = 64 lanes x 16B = K=64.
// Logical k (hi=lane>>5, i) of frag f -> model index rho = 64f + (i>>4)*32 +
// sigma4(i&15) + 4*hi, sigma4(q) = (q&3)+8*(q>>2). Producer C-register nibbles
// land verbatim in the consumer B-frag slot (R12-verified). W sign-folded;
// thresholds in sigma order init the f32 accumulator (exact integers).
#define OFF_ACTA 0u            // 8 MB  (packed X, fp4)
#define OFF_ACTB 16777216u     // (unused — kept for layout stability)
#define OFF_WA1  33554432u     // 512 KB
#define OFF_WA2  34603008u     // 512 KB
#define OFF_WA3  35651584u     // 512 KB
#define OFF_WA4  36700160u     // 16 KB (10 rows + 22 zero rows)
#define OFF_TH   36732928u     // 3*1024 int (sigma order)

// ---------------------------------------------------------------------------
// bytes {0x01,0xFF,0x00} -> fp4 nibbles {+1=0x2,-1=0xA,0=0x0}; 8 bytes -> dword
__device__ __forceinline__ uint32 nib8(uint32 lo, uint32 hb) {
    uint32 r = 0u;
#pragma unroll
    for (int j = 0; j < 4; ++j) {
        uint32 b = (lo >> (8 * j)) & 0xFFu;
        r |= (((b & 8u) | ((b & 1u) << 1)) << (4 * j));
    }
#pragma unroll
    for (int j = 0; j < 4; ++j) {
        uint32 b = (hb >> (8 * j)) & 0xFFu;
        r |= (((b & 8u) | ((b & 1u) << 1)) << (4 * j + 16));
    }
    return r;
}

// ---------------------------------------------------------------------------
// prep (R12-verified, unchanged): binarize, sign-fold W, emit fp4 rho frags.
__global__ void __launch_bounds__(256) prep_kernel(
    const float* __restrict__ x,
    const float* __restrict__ W1, const float* __restrict__ W2,
    const float* __restrict__ W3, const float* __restrict__ W4,
    const float* __restrict__ g1, const float* __restrict__ b1,
    const float* __restrict__ m1, const float* __restrict__ v1,
    const float* __restrict__ g2, const float* __restrict__ b2,
    const float* __restrict__ m2, const float* __restrict__ v2,
    const float* __restrict__ g3, const float* __restrict__ b3,
    const float* __restrict__ m3, const float* __restrict__ v3,
    char* __restrict__ actA, char* __restrict__ wa1, char* __restrict__ wa2,
    char* __restrict__ wa3, char* __restrict__ wa4, int* __restrict__ TH)
{
    int b = blockIdx.x;
    if (b == 609) {                       // thresholds, sign-folded, sigma order
        for (int gid = threadIdx.x; gid < 3072; gid += 256) {
            int l = gid >> 10, j = gid & 1023;
            const float *g, *bb, *m, *v;
            if (l == 0)      { g = g1; bb = b1; m = m1; v = v1; }
            else if (l == 1) { g = g2; bb = b2; m = m2; v = v2; }
            else             { g = g3; bb = b3; m = m3; v = v3; }
            double gd = (double)g[j], bd = (double)bb[j], md = (double)m[j], vd = (double)v[j];
            double s = gd / sqrt(vd + 1e-5);
            int t2;
            if (s > 0.0)      t2 = (int)ceil(md - bd / s);           // bit = h >= t2
            else if (s < 0.0) t2 = -(int)floor(md - bd / s);         // folded
            else              t2 = (bd >= 0.0) ? -2000000 : 2000000; // always / never
            int sidx = (j >> 5) * 32 + ((j >> 2) & 1) * 16 + (j & 3) + 4 * ((j & 31) >> 3);
            TH[l * 1024 + sidx] = t2;
        }
        return;
    }

    const float* src; char* dst; float thr; int nrows; int dblk;
    const float* gp = nullptr;
    if (b < 512)      { src = x  + (size_t)b * 32768;            dst = actA; dblk = b;      thr = 0.5f; nrows = 32; }
    else if (b < 544) { int mb = b - 512; src = W1 + (size_t)mb * 32768; dst = wa1; dblk = mb; thr = 0.0f; nrows = 32; gp = g1; }
    else if (b < 576) { int mb = b - 544; src = W2 + (size_t)mb * 32768; dst = wa2; dblk = mb; thr = 0.0f; nrows = 32; gp = g2; }
    else if (b < 608) { int mb = b - 576; src = W3 + (size_t)mb * 32768; dst = wa3; dblk = mb; thr = 0.0f; nrows = 32; gp = g3; }
    else              { src = W4; dst = wa4; dblk = 0; thr = 0.0f; nrows = 10; }

    __shared__ unsigned char T[32][1040];
#pragma unroll
    for (int u = 0; u < 8; ++u) {
        int unit = threadIdx.x + u * 256;      // 0..2047
        int row  = unit >> 6;                  // 0..31
        int c16  = (unit & 63) << 4;           // col base (16 floats)
        uint32 wb0 = 0, wb1 = 0, wb2 = 0, wb3 = 0;   // 0x00 pad rows -> fp4 zero
        if (row < nrows) {
            bool flipb = gp && (gp[dblk * 32 + row] < 0.0f);
            const float* p = src + (size_t)row * 1024 + c16;
            float4 f0 = *(const float4*)(p + 0);
            float4 f1 = *(const float4*)(p + 4);
            float4 f2 = *(const float4*)(p + 8);
            float4 f3 = *(const float4*)(p + 12);
#define BY(f) ((((f) >= thr) != flipb) ? 0x01u : 0xFFu)
            wb0 = BY(f0.x) | (BY(f0.y)<<8) | (BY(f0.z)<<16) | (BY(f0.w)<<24);
            wb1 = BY(f1.x) | (BY(f1.y)<<8) | (BY(f1.z)<<16) | (BY(f1.w)<<24);
            wb2 = BY(f2.x) | (BY(f2.y)<<8) | (BY(f2.z)<<16) | (BY(f2.w)<<24);
            wb3 = BY(f3.x) | (BY(f3.y)<<8) | (BY(f3.z)<<16) | (BY(f3.w)<<24);
#undef BY
        }
        *(uint4*)&T[row][c16] = make_uint4(wb0, wb1, wb2, wb3);
    }
    __syncthreads();

    int lane = threadIdx.x & 63;
    int wq   = threadIdx.x >> 6;               // 0..3
    int c    = lane & 31;
    int hi   = lane >> 5;
#pragma unroll
    for (int u = 0; u < 4; ++u) {
        int f = wq * 4 + u;
        uint32 dw0, dw1, dw2, dw3;
        {
            int base = 64 * f + 4 * hi;
            dw0 = nib8(*(const uint32*)&T[c][base],      *(const uint32*)&T[c][base + 8]);
            dw1 = nib8(*(const uint32*)&T[c][base + 16], *(const uint32*)&T[c][base + 24]);
            dw2 = nib8(*(const uint32*)&T[c][base + 32], *(const uint32*)&T[c][base + 40]);
            dw3 = nib8(*(const uint32*)&T[c][base + 48], *(const uint32*)&T[c][base + 56]);
        }
        *(uint4*)(dst + (((size_t)dblk * 16 + f) * 64 + lane) * 16) = make_uint4(dw0, dw1, dw2, dw3);
    }
}

// ---------------------------------------------------------------------------
__device__ __forceinline__ void gload16(const v4i* gsrc, v4i* ldst) {
    __builtin_amdgcn_global_load_lds(
        (const __attribute__((address_space(1))) void*)gsrc,
        (__attribute__((address_space(3))) void*)ldst, 16, 0, 0);
}

// fp4 MX MFMA, scale = 1.0 (E8M0 0x7F); cbsz=4 (fp4), blgp=4 (fp4)
__device__ __forceinline__ v16f MFMA4(v4i a, v4i b, v16f c) {
    v8i av; av[0] = a[0]; av[1] = a[1]; av[2] = a[2]; av[3] = a[3];
    av[4] = 0; av[5] = 0; av[6] = 0; av[7] = 0;
    v8i bv; bv[0] = b[0]; bv[1] = b[1]; bv[2] = b[2]; bv[3] = b[3];
    bv[4] = 0; bv[5] = 0; bv[6] = 0; bv[7] = 0;
    return __builtin_amdgcn_mfma_scale_f32_32x32x64_f8f6f4(
        av, bv, c, 4, 4, 0, 0x7F7F7F7F, 0, 0x7F7F7F7F);
}

// ---------------------------------------------------------------------------
// R15 net: R13/R14 structure with REAL pipeline depth. R14's bug: stages were
// issued and vmcnt(0)-drained within the SAME step (zero cover) -> all waves
// waited on contended L2 every step (48 x ~2200cyc ~= measured 50us). Fix
// (T4 counted-vmcnt + triple buffer): step g stages frag g+2 into Wb[(g+2)%3]
// and ends with vmcnt(2) -- waits only until the 2 newest loads (S(g+2))
// remain, forcing S(g+1) (issued a FULL step ago) complete. In-order vmcnt
// retirement (m135) + exactly 2 stages/thread/step make the count exact.
// Never drain to 0 in the loop; only the last 2 steps of layer 3 (nothing
// staged) use vmcnt(0). LDS = Hs 32K + Wb 3x32K = 128 KB, 1 block/CU.
__global__ void __launch_bounds__(1024, 4) net_kernel(
    const v4i* __restrict__ Xp,  const v4i* __restrict__ Wp1,
    const v4i* __restrict__ Wp2, const v4i* __restrict__ Wp3,
    const v4i* __restrict__ Wp4, const int* __restrict__ TH,
    const float* __restrict__ tw, const float* __restrict__ tb,
    const float* __restrict__ tm, const float* __restrict__ tv,
    float* __restrict__ out)
{
    __shared__ v4i Hs[2048];               // 32 KB: frag g = nb*16+f at g*64+lane
    __shared__ v4i Wb[3][2048];            // 3 x 32 KB ring: buf(g) = g%3
    const int tid  = threadIdx.x;
    const int lane = tid & 63;
    const int wv   = tid >> 6;             // 0..15
    const int hi   = lane >> 5;
    const int blk  = blockIdx.x;           // 0..255, owns cols blk*64..+63

    // ---- prologue: X -> Hs (oldest), L0 frag0 -> Wb[0], L0 frag1 -> Wb[1] ----
    {
        const v4i* src = Xp + (size_t)blk * 2048;
        gload16(src + 0 * 1024 + wv * 64 + lane, &Hs[0 * 1024 + wv * 64]);
        gload16(src + 1 * 1024 + wv * 64 + lane, &Hs[1 * 1024 + wv * 64]);
        gload16(Wp1 + (size_t)(wv * 16 + 0) * 64 + lane,        &Wb[0][wv * 64]);
        gload16(Wp1 + (size_t)((16 + wv) * 16 + 0) * 64 + lane, &Wb[0][1024 + wv * 64]);
        gload16(Wp1 + (size_t)(wv * 16 + 1) * 64 + lane,        &Wb[1][wv * 64]);
        gload16(Wp1 + (size_t)((16 + wv) * 16 + 1) * 64 + lane, &Wb[1][1024 + wv * 64]);
    }
    // wait X + frag0 (oldest 4); frag1 (2 newest) stays in flight
    asm volatile("s_waitcnt vmcnt(2)" ::: "memory");
    __builtin_amdgcn_s_barrier();

    const int mt0 = wv * 2, mt1 = wv * 2 + 1;
    int bcur = 0;                          // ring position, advances every step

#pragma unroll 1
    for (int l = 0; l < 3; ++l) {
        const int* thl = TH + l * 1024;

        // f32 acc pre-initialized with -T2 (exact integers)
        v16f acc00, acc01, acc10, acc11;
        {
            const int4* t0 = (const int4*)(thl + mt0 * 32 + hi * 16);
            const int4* t1 = (const int4*)(thl + mt1 * 32 + hi * 16);
#pragma unroll
            for (int g = 0; g < 4; ++g) {
                int4 ta = t0[g], tc = t1[g];
                acc00[4*g+0] = -(float)ta.x; acc00[4*g+1] = -(float)ta.y;
                acc00[4*g+2] = -(float)ta.z; acc00[4*g+3] = -(float)ta.w;
                acc10[4*g+0] = -(float)tc.x; acc10[4*g+1] = -(float)tc.y;
                acc10[4*g+2] = -(float)tc.z; acc10[4*g+3] = -(float)tc.w;
            }
#pragma unroll
            for (int q = 0; q < 16; ++q) { acc01[q] = acc00[q]; acc11[q] = acc10[q]; }
        }

#pragma unroll 1
        for (int fs = 0; fs < 16; ++fs) {
            const v4i* Wc = &Wb[bcur][0];
            const int bstg = (bcur + 2 >= 3) ? (bcur - 1) : (bcur + 2);   // (bcur+2)%3
            v4i* Wn = &Wb[bstg][0];
            bool tail = false;
            if (fs < 14) {                      // stage this layer's frag fs+2
                const v4i* W = (l == 0) ? Wp1 : (l == 1) ? Wp2 : Wp3;
                gload16(W + (size_t)(wv * 16 + fs + 2) * 64 + lane,        Wn + wv * 64);
                gload16(W + (size_t)((16 + wv) * 16 + fs + 2) * 64 + lane, Wn + 1024 + wv * 64);
            } else if (l < 2) {                 // stage next layer's frag fs-14
                const v4i* W2 = (l == 0) ? Wp2 : Wp3;
                gload16(W2 + (size_t)(wv * 16 + fs - 14) * 64 + lane,        Wn + wv * 64);
                gload16(W2 + (size_t)((16 + wv) * 16 + fs - 14) * 64 + lane, Wn + 1024 + wv * 64);
            } else tail = true;                 // l==2, fs>=14: nothing staged

            v4i a0 = Wc[mt0 * 64 + lane];
            v4i a1 = Wc[mt1 * 64 + lane];
            v4i b0 = Hs[fs * 64 + lane];
            v4i b1 = Hs[(16 + fs) * 64 + lane];
            acc00 = MFMA4(a0, b0, acc00);
            acc01 = MFMA4(a0, b1, acc01);
            acc10 = MFMA4(a1, b0, acc10);
            acc11 = MFMA4(a1, b1, acc11);

            // counted wait: keep only the 2 newest (S(g+2)) in flight =>
            // S(g+1), issued a full step ago, is complete. Tail: drain.
            if (tail) asm volatile("s_waitcnt vmcnt(0)" ::: "memory");
            else      asm volatile("s_waitcnt vmcnt(2)" ::: "memory");
            __builtin_amdgcn_s_barrier();
            bcur = (bcur == 2) ? 0 : bcur + 1;
        }

        // pack: nibble = 0x2 (+1) if h>=0 else 0xA (-1)
#define NB4(h) (((h) >= 0.0f) ? 2u : 10u)
        uint32 p00a = 0, p00b = 0, p01a = 0, p01b = 0;
        uint32 p10a = 0, p10b = 0, p11a = 0, p11b = 0;
#pragma unroll
        for (int j = 0; j < 8; ++j) {
            p00a |= NB4(acc00[j]) << (4 * j);  p00b |= NB4(acc00[8 + j]) << (4 * j);
            p01a |= NB4(acc01[j]) << (4 * j);  p01b |= NB4(acc01[8 + j]) << (4 * j);
            p10a |= NB4(acc10[j]) << (4 * j);  p10b |= NB4(acc10[8 + j]) << (4 * j);
            p11a |= NB4(acc11[j]) << (4 * j);  p11b |= NB4(acc11[8 + j]) << (4 * j);
        }
#undef NB4

        __syncthreads();                   // all waves done READING Hs
        {
            v4i o;
            o[0] = (int)p00a; o[1] = (int)p00b; o[2] = (int)p10a; o[3] = (int)p10b;
            Hs[(0 * 16 + wv) * 64 + lane] = o;       // nb0
            o[0] = (int)p01a; o[1] = (int)p01b; o[2] = (int)p11a; o[3] = (int)p11b;
            Hs[(16 + wv) * 64 + lane] = o;           // nb1
        }
        __syncthreads();                   // new layer visible to all waves
    }

    // ---- final 1024 -> 10 (W4 zero-padded rows = fp4 0.0) + TensorNorm ----
    if (wv < 2) {
        const int nb = wv;
        v16f acc;
#pragma unroll
        for (int z = 0; z < 16; ++z) acc[z] = 0.0f;
#pragma unroll
        for (int f = 0; f < 16; ++f) {
            v4i av = Wp4[f * 64 + lane];
            v4i bv = Hs[(nb * 16 + f) * 64 + lane];
            acc = MFMA4(av, bv, acc);
        }
        double sc  = (double)tw[0] / sqrt((double)tv[0] + 1e-4);
        double off = (double)tb[0] - (double)tm[0] * sc;
        int colg = blk * 64 + nb * 32 + (lane & 31);
#pragma unroll
        for (int q = 0; q < 8; ++q) {
            int rr = (q & 3) + 8 * (q >> 2) + 4 * hi;
            if (rr < 10)
                out[(size_t)colg * 10 + rr] = (float)((double)acc[q] * sc + off);
        }
    }
}

// ---------------------------------------------------------------------------
extern "C" void kernel_launch(void* const* d_in, const int* in_sizes, int n_in,
                              void* d_out, int out_size, void* d_ws, size_t ws_size,
                              hipStream_t stream) {
    const float* x  = (const float*)d_in[0];
    const float* W1 = (const float*)d_in[1];
    const float* W2 = (const float*)d_in[2];
    const float* W3 = (const float*)d_in[3];
    const float* W4 = (const float*)d_in[4];
    const float* g1 = (const float*)d_in[5];
    const float* b1 = (const float*)d_in[6];
    const float* m1 = (const float*)d_in[7];
    const float* v1 = (const float*)d_in[8];
    const float* g2 = (const float*)d_in[9];
    const float* b2 = (const float*)d_in[10];
    const float* m2 = (const float*)d_in[11];
    const float* v2 = (const float*)d_in[12];
    const float* g3 = (const float*)d_in[13];
    const float* b3 = (const float*)d_in[14];
    const float* m3 = (const float*)d_in[15];
    const float* v3 = (const float*)d_in[16];
    const float* tw = (const float*)d_in[17];
    const float* tb = (const float*)d_in[18];
    const float* tm = (const float*)d_in[19];
    const float* tv = (const float*)d_in[20];

    char* ws = (char*)d_ws;
    char* actA = ws + OFF_ACTA;
    char* wa1  = ws + OFF_WA1;
    char* wa2  = ws + OFF_WA2;
    char* wa3  = ws + OFF_WA3;
    char* wa4  = ws + OFF_WA4;
    int*  TH   = (int*)(ws + OFF_TH);

    prep_kernel<<<610, 256, 0, stream>>>(x, W1, W2, W3, W4,
                                         g1, b1, m1, v1, g2, b2, m2, v2,
                                         g3, b3, m3, v3,
                                         actA, wa1, wa2, wa3, wa4, TH);

    net_kernel<<<256, 1024, 0, stream>>>((const v4i*)actA,
                                         (const v4i*)wa1, (const v4i*)wa2,
                                         (const v4i*)wa3, (const v4i*)wa4,
                                         TH, tw, tb, tm, tv, (float*)d_out);
}

// Round 16
// 171.773 us; speedup vs baseline: 1.1035x; 1.0679x over previous
//
#include <hip/hip_runtime.h>
#include <stdint.h>

typedef int   v4i  __attribute__((ext_vector_type(4)));
typedef int   v8i  __attribute__((ext_vector_type(8)));
typedef float v16f __attribute__((ext_vector_type(16)));
typedef unsigned int uint32;

#define BATCH 16384
#define FEAT  1024

// ---- workspace layout (bytes) ----
// MXFP4 everywhere (+1=0x2, -1=0xA, pad=0x0). Frag = 64 lanes x 16B = K=64.
// Logical k (hi=lane>>5, i) of frag f -> model index rho = 64f + (i>>4)*32 +
// sigma4(i&15) + 4*hi, sigma4(q) = (q&3)+8*(q>>2). Producer C-register nibbles
// land verbatim in the consumer B-frag slot (R12-verified). W sign-folded;
// thresholds in sigma order init the f32 accumulator (exact integers).
// R16: X binarization fused into net (no actA round-trip); prep is W/TH-only.
#define OFF_WA1  33554432u     // 512 KB
#define OFF_WA2  34603008u     // 512 KB
#define OFF_WA3  35651584u     // 512 KB
#define OFF_WA4  36700160u     // 16 KB (10 rows + 22 zero rows)
#define OFF_TH   36732928u     // 3*1024 int (sigma order)

// ---------------------------------------------------------------------------
// bytes {0x01,0xFF,0x00} -> fp4 nibbles {+1=0x2,-1=0xA,0=0x0}; 8 bytes -> dword
__device__ __forceinline__ uint32 nib8(uint32 lo, uint32 hb) {
    uint32 r = 0u;
#pragma unroll
    for (int j = 0; j < 4; ++j) {
        uint32 b = (lo >> (8 * j)) & 0xFFu;
        r |= (((b & 8u) | ((b & 1u) << 1)) << (4 * j));
    }
#pragma unroll
    for (int j = 0; j < 4; ++j) {
        uint32 b = (hb >> (8 * j)) & 0xFFu;
        r |= (((b & 8u) | ((b & 1u) << 1)) << (4 * j + 16));
    }
    return r;
}

// ---------------------------------------------------------------------------
// prep (R16: W/TH only — X moved into net). 98 blocks:
// b<32: W1 | <64: W2 | <96: W3 | 96: W4 (pad) | 97: TH (sigma order).
__global__ void __launch_bounds__(256) prep_kernel(
    const float* __restrict__ W1, const float* __restrict__ W2,
    const float* __restrict__ W3, const float* __restrict__ W4,
    const float* __restrict__ g1, const float* __restrict__ b1,
    const float* __restrict__ m1, const float* __restrict__ v1,
    const float* __restrict__ g2, const float* __restrict__ b2,
    const float* __restrict__ m2, const float* __restrict__ v2,
    const float* __restrict__ g3, const float* __restrict__ b3,
    const float* __restrict__ m3, const float* __restrict__ v3,
    char* __restrict__ wa1, char* __restrict__ wa2,
    char* __restrict__ wa3, char* __restrict__ wa4, int* __restrict__ TH)
{
    int b = blockIdx.x;
    if (b == 97) {                        // thresholds, sign-folded, sigma order
        for (int gid = threadIdx.x; gid < 3072; gid += 256) {
            int l = gid >> 10, j = gid & 1023;
            const float *g, *bb, *m, *v;
            if (l == 0)      { g = g1; bb = b1; m = m1; v = v1; }
            else if (l == 1) { g = g2; bb = b2; m = m2; v = v2; }
            else             { g = g3; bb = b3; m = m3; v = v3; }
            double gd = (double)g[j], bd = (double)bb[j], md = (double)m[j], vd = (double)v[j];
            double s = gd / sqrt(vd + 1e-5);
            int t2;
            if (s > 0.0)      t2 = (int)ceil(md - bd / s);           // bit = h >= t2
            else if (s < 0.0) t2 = -(int)floor(md - bd / s);         // folded
            else              t2 = (bd >= 0.0) ? -2000000 : 2000000; // always / never
            int sidx = (j >> 5) * 32 + ((j >> 2) & 1) * 16 + (j & 3) + 4 * ((j & 31) >> 3);
            TH[l * 1024 + sidx] = t2;
        }
        return;
    }

    const float* src; char* dst; int nrows; int dblk;
    const float* gp = nullptr;
    if (b < 32)       { dblk = b;      src = W1 + (size_t)dblk * 32768; dst = wa1; nrows = 32; gp = g1; }
    else if (b < 64)  { dblk = b - 32; src = W2 + (size_t)dblk * 32768; dst = wa2; nrows = 32; gp = g2; }
    else if (b < 96)  { dblk = b - 64; src = W3 + (size_t)dblk * 32768; dst = wa3; nrows = 32; gp = g3; }
    else              { dblk = 0;      src = W4;                        dst = wa4; nrows = 10; }

    __shared__ unsigned char T[32][1040];
#pragma unroll
    for (int u = 0; u < 8; ++u) {
        int unit = threadIdx.x + u * 256;      // 0..2047
        int row  = unit >> 6;                  // 0..31
        int c16  = (unit & 63) << 4;           // col base (16 floats)
        uint32 wb0 = 0, wb1 = 0, wb2 = 0, wb3 = 0;   // 0x00 pad rows -> fp4 zero
        if (row < nrows) {
            bool flipb = gp && (gp[dblk * 32 + row] < 0.0f);
            const float* p = src + (size_t)row * 1024 + c16;
            float4 f0 = *(const float4*)(p + 0);
            float4 f1 = *(const float4*)(p + 4);
            float4 f2 = *(const float4*)(p + 8);
            float4 f3 = *(const float4*)(p + 12);
#define BY(f) ((((f) >= 0.0f) != flipb) ? 0x01u : 0xFFu)
            wb0 = BY(f0.x) | (BY(f0.y)<<8) | (BY(f0.z)<<16) | (BY(f0.w)<<24);
            wb1 = BY(f1.x) | (BY(f1.y)<<8) | (BY(f1.z)<<16) | (BY(f1.w)<<24);
            wb2 = BY(f2.x) | (BY(f2.y)<<8) | (BY(f2.z)<<16) | (BY(f2.w)<<24);
            wb3 = BY(f3.x) | (BY(f3.y)<<8) | (BY(f3.z)<<16) | (BY(f3.w)<<24);
#undef BY
        }
        *(uint4*)&T[row][c16] = make_uint4(wb0, wb1, wb2, wb3);
    }
    __syncthreads();

    int lane = threadIdx.x & 63;
    int wq   = threadIdx.x >> 6;               // 0..3
    int c    = lane & 31;
    int hi   = lane >> 5;
#pragma unroll
    for (int u = 0; u < 4; ++u) {
        int f = wq * 4 + u;
        uint32 dw0, dw1, dw2, dw3;
        {
            int base = 64 * f + 4 * hi;
            dw0 = nib8(*(const uint32*)&T[c][base],      *(const uint32*)&T[c][base + 8]);
            dw1 = nib8(*(const uint32*)&T[c][base + 16], *(const uint32*)&T[c][base + 24]);
            dw2 = nib8(*(const uint32*)&T[c][base + 32], *(const uint32*)&T[c][base + 40]);
            dw3 = nib8(*(const uint32*)&T[c][base + 48], *(const uint32*)&T[c][base + 56]);
        }
        *(uint4*)(dst + (((size_t)dblk * 16 + f) * 64 + lane) * 16) = make_uint4(dw0, dw1, dw2, dw3);
    }
}

// ---------------------------------------------------------------------------
// fp4 MX MFMA, scale = 1.0 (E8M0 0x7F); cbsz=4 (fp4), blgp=4 (fp4)
__device__ __forceinline__ v16f MFMA4(v4i a, v4i b, v16f c) {
    v8i av; av[0] = a[0]; av[1] = a[1]; av[2] = a[2]; av[3] = a[3];
    av[4] = 0; av[5] = 0; av[6] = 0; av[7] = 0;
    v8i bv; bv[0] = b[0]; bv[1] = b[1]; bv[2] = b[2]; bv[3] = b[3];
    bv[4] = 0; bv[5] = 0; bv[6] = 0; bv[7] = 0;
    return __builtin_amdgcn_mfma_scale_f32_32x32x64_f8f6f4(
        av, bv, c, 4, 4, 0, 0x7F7F7F7F, 0, 0x7F7F7F7F);
}

// ---------------------------------------------------------------------------
// R16 net: R12-verified loop (direct L2 A-stream, no W staging -- the
// R13/14/15 LDS-staging line measured WORSE) + X binarization fused into the
// prologue (each block packs its own 64 batch rows of x: kills the actA
// round-trip and shrinks prep to W-only). Skew now per-block+per-wave
// ((wv+blk)&15): de-aligns cross-block reads of the same W lines at L2.
__global__ void __launch_bounds__(1024, 4) net_kernel(
    const float* __restrict__ x,
    const v4i* __restrict__ Wp1, const v4i* __restrict__ Wp2,
    const v4i* __restrict__ Wp3, const v4i* __restrict__ Wp4,
    const int* __restrict__ TH,
    const float* __restrict__ tw, const float* __restrict__ tb,
    const float* __restrict__ tm, const float* __restrict__ tv,
    float* __restrict__ out)
{
    __shared__ v4i Hs[2048];               // 32 KB: frag g = nb*16+f at g*64+lane
    __shared__ unsigned char T[32][1040];  // 33 KB staging for X binarize
    const int tid  = threadIdx.x;
    const int lane = tid & 63;
    const int wv   = tid >> 6;             // 0..15
    const int hi   = lane >> 5;
    const int blk  = blockIdx.x;           // 0..255, owns batch rows blk*64..+63

    // ---- fused X binarize: 2 units of 32 batch rows -> Hs fp4 frags ----
#pragma unroll 1
    for (int unit = 0; unit < 2; ++unit) {
        const float* src = x + ((size_t)blk * 64 + unit * 32) * 1024;
#pragma unroll
        for (int u = 0; u < 2; ++u) {
            int uu  = tid + u * 1024;          // 0..2047
            int row = uu >> 6;                 // 0..31
            int c16 = (uu & 63) << 4;          // col base (16 floats)
            const float* p = src + (size_t)row * 1024 + c16;
            float4 f0 = *(const float4*)(p + 0);
            float4 f1 = *(const float4*)(p + 4);
            float4 f2 = *(const float4*)(p + 8);
            float4 f3 = *(const float4*)(p + 12);
            // binarize(2x-1): +1 iff x >= 0.5 (x=0.5 -> 0 -> +1, matches ref)
#define BY(f) (((f) >= 0.5f) ? 0x01u : 0xFFu)
            uint32 wb0 = BY(f0.x) | (BY(f0.y)<<8) | (BY(f0.z)<<16) | (BY(f0.w)<<24);
            uint32 wb1 = BY(f1.x) | (BY(f1.y)<<8) | (BY(f1.z)<<16) | (BY(f1.w)<<24);
            uint32 wb2 = BY(f2.x) | (BY(f2.y)<<8) | (BY(f2.z)<<16) | (BY(f2.w)<<24);
            uint32 wb3 = BY(f3.x) | (BY(f3.y)<<8) | (BY(f3.z)<<16) | (BY(f3.w)<<24);
#undef BY
            *(uint4*)&T[row][c16] = make_uint4(wb0, wb1, wb2, wb3);
        }
        __syncthreads();
        {   // gather: one frag per wave (f = wv), nb tile = unit
            int c = lane & 31;
            int base = 64 * wv + 4 * hi;
            uint32 dw0 = nib8(*(const uint32*)&T[c][base],      *(const uint32*)&T[c][base + 8]);
            uint32 dw1 = nib8(*(const uint32*)&T[c][base + 16], *(const uint32*)&T[c][base + 24]);
            uint32 dw2 = nib8(*(const uint32*)&T[c][base + 32], *(const uint32*)&T[c][base + 40]);
            uint32 dw3 = nib8(*(const uint32*)&T[c][base + 48], *(const uint32*)&T[c][base + 56]);
            v4i o; o[0] = (int)dw0; o[1] = (int)dw1; o[2] = (int)dw2; o[3] = (int)dw3;
            Hs[(unit * 16 + wv) * 64 + lane] = o;
        }
        __syncthreads();
    }

    const int mt0 = wv * 2, mt1 = wv * 2 + 1;
    const int f0s = (wv + blk) & 15;       // per-block + per-wave ring skew

#pragma unroll 1
    for (int l = 0; l < 3; ++l) {
        const v4i* W = (l == 0) ? Wp1 : (l == 1) ? Wp2 : Wp3;
        const int* thl = TH + l * 1024;

        // f32 acc pre-initialized with -T2 (exact integers)
        v16f acc00, acc01, acc10, acc11;
        {
            const int4* t0 = (const int4*)(thl + mt0 * 32 + hi * 16);
            const int4* t1 = (const int4*)(thl + mt1 * 32 + hi * 16);
#pragma unroll
            for (int g = 0; g < 4; ++g) {
                int4 ta = t0[g], tc = t1[g];
                acc00[4*g+0] = -(float)ta.x; acc00[4*g+1] = -(float)ta.y;
                acc00[4*g+2] = -(float)ta.z; acc00[4*g+3] = -(float)ta.w;
                acc10[4*g+0] = -(float)tc.x; acc10[4*g+1] = -(float)tc.y;
                acc10[4*g+2] = -(float)tc.z; acc10[4*g+3] = -(float)tc.w;
            }
#pragma unroll
            for (int q = 0; q < 16; ++q) { acc01[q] = acc00[q]; acc11[q] = acc10[q]; }
        }

        const v4i* A0 = W + (size_t)mt0 * 16 * 64 + lane;
        const v4i* A1 = W + (size_t)mt1 * 16 * 64 + lane;
#pragma unroll 2
        for (int fs = 0; fs < 16; ++fs) {
            const int f = (fs + f0s) & 15;     // skewed ring (named scalar)
            v4i b0 = Hs[f * 64 + lane];
            v4i b1 = Hs[(16 + f) * 64 + lane];
            v4i a0 = A0[f * 64];
            v4i a1 = A1[f * 64];
            acc00 = MFMA4(a0, b0, acc00);
            acc01 = MFMA4(a0, b1, acc01);
            acc10 = MFMA4(a1, b0, acc10);
            acc11 = MFMA4(a1, b1, acc11);
        }

        // pack: nibble = 0x2 (+1) if h>=0 else 0xA (-1)
#define NB4(h) (((h) >= 0.0f) ? 2u : 10u)
        uint32 p00a = 0, p00b = 0, p01a = 0, p01b = 0;
        uint32 p10a = 0, p10b = 0, p11a = 0, p11b = 0;
#pragma unroll
        for (int j = 0; j < 8; ++j) {
            p00a |= NB4(acc00[j]) << (4 * j);  p00b |= NB4(acc00[8 + j]) << (4 * j);
            p01a |= NB4(acc01[j]) << (4 * j);  p01b |= NB4(acc01[8 + j]) << (4 * j);
            p10a |= NB4(acc10[j]) << (4 * j);  p10b |= NB4(acc10[8 + j]) << (4 * j);
            p11a |= NB4(acc11[j]) << (4 * j);  p11b |= NB4(acc11[8 + j]) << (4 * j);
        }
#undef NB4

        __syncthreads();                   // all waves done READING Hs
        {
            v4i o;
            o[0] = (int)p00a; o[1] = (int)p00b; o[2] = (int)p10a; o[3] = (int)p10b;
            Hs[(0 * 16 + wv) * 64 + lane] = o;       // nb0
            o[0] = (int)p01a; o[1] = (int)p01b; o[2] = (int)p11a; o[3] = (int)p11b;
            Hs[(16 + wv) * 64 + lane] = o;           // nb1
        }
        __syncthreads();                   // new layer visible to all waves
    }

    // ---- final 1024 -> 10 (W4 zero-padded rows = fp4 0.0) + TensorNorm ----
    if (wv < 2) {
        const int nb = wv;
        v16f acc;
#pragma unroll
        for (int z = 0; z < 16; ++z) acc[z] = 0.0f;
#pragma unroll
        for (int f = 0; f < 16; ++f) {
            v4i av = Wp4[f * 64 + lane];
            v4i bv = Hs[(nb * 16 + f) * 64 + lane];
            acc = MFMA4(av, bv, acc);
        }
        double sc  = (double)tw[0] / sqrt((double)tv[0] + 1e-4);
        double off = (double)tb[0] - (double)tm[0] * sc;
        int colg = blk * 64 + nb * 32 + (lane & 31);
#pragma unroll
        for (int q = 0; q < 8; ++q) {
            int rr = (q & 3) + 8 * (q >> 2) + 4 * hi;
            if (rr < 10)
                out[(size_t)colg * 10 + rr] = (float)((double)acc[q] * sc + off);
        }
    }
}

// ---------------------------------------------------------------------------
extern "C" void kernel_launch(void* const* d_in, const int* in_sizes, int n_in,
                              void* d_out, int out_size, void* d_ws, size_t ws_size,
                              hipStream_t stream) {
    const float* x  = (const float*)d_in[0];
    const float* W1 = (const float*)d_in[1];
    const float* W2 = (const float*)d_in[2];
    const float* W3 = (const float*)d_in[3];
    const float* W4 = (const float*)d_in[4];
    const float* g1 = (const float*)d_in[5];
    const float* b1 = (const float*)d_in[6];
    const float* m1 = (const float*)d_in[7];
    const float* v1 = (const float*)d_in[8];
    const float* g2 = (const float*)d_in[9];
    const float* b2 = (const float*)d_in[10];
    const float* m2 = (const float*)d_in[11];
    const float* v2 = (const float*)d_in[12];
    const float* g3 = (const float*)d_in[13];
    const float* b3 = (const float*)d_in[14];
    const float* m3 = (const float*)d_in[15];
    const float* v3 = (const float*)d_in[16];
    const float* tw = (const float*)d_in[17];
    const float* tb = (const float*)d_in[18];
    const float* tm = (const float*)d_in[19];
    const float* tv = (const float*)d_in[20];

    char* ws = (char*)d_ws;
    char* wa1  = ws + OFF_WA1;
    char* wa2  = ws + OFF_WA2;
    char* wa3  = ws + OFF_WA3;
    char* wa4  = ws + OFF_WA4;
    int*  TH   = (int*)(ws + OFF_TH);

    prep_kernel<<<98, 256, 0, stream>>>(W1, W2, W3, W4,
                                        g1, b1, m1, v1, g2, b2, m2, v2,
                                        g3, b3, m3, v3,
                                        wa1, wa2, wa3, wa4, TH);

    net_kernel<<<256, 1024, 0, stream>>>(x,
                                         (const v4i*)wa1, (const v4i*)wa2,
                                         (const v4i*)wa3, (const v4i*)wa4,
                                         TH, tw, tb, tm, tv, (float*)d_out);
}